// Round 5
// baseline (134.283 us; speedup 1.0000x reference)
//
#include <hip/hip_runtime.h>
#include <hip/hip_fp16.h>

#define T_TOK 200
#define EMB   128
#define LPAD  4

typedef _Float16 f16x8 __attribute__((ext_vector_type(8)));
typedef float    f32x4 __attribute__((ext_vector_type(4)));

// ws layout: Wpack fp16 (458752 B) | embH (25600000 B)
// Wpack fp16 offsets: L1 0, L2 65536, L3 196608 (total 229376 fp16)
#define WP2        65536
#define WP3        196608
#define EMBH_OFF   458752UL
#define WS_NEED    (EMBH_OFF + 25600000UL)

// ---- prep: emb fp32->fp16 + W pack into MFMA B-frag order (R12-proven) ----
__global__ __launch_bounds__(256) void prep_kernel(
    const float* __restrict__ emb,
    const float* __restrict__ W1, const float* __restrict__ W2,
    const float* __restrict__ W3,
    __half* __restrict__ embH, __half* __restrict__ WpH)
{
    int bid = blockIdx.x;
    if (bid < 6250) {
        size_t i = ((size_t)bid * 256 + threadIdx.x) * 8;   // 12.8M floats exact
        float4 a = *(const float4*)(emb + i);
        float4 b = *(const float4*)(emb + i + 4);
        __half2 hh[4];
        hh[0] = __floats2half2_rn(a.x, a.y);
        hh[1] = __floats2half2_rn(a.z, a.w);
        hh[2] = __floats2half2_rn(b.x, b.y);
        hh[3] = __floats2half2_rn(b.z, b.w);
        *(float4*)(embH + i) = *(float4*)hh;
    } else {
        int t = (bid - 6250) * 256 + threadIdx.x;           // < 28672
        const float* Wsrc; int FIN, KC, dstbase, e;
        if (t < 8192)       { Wsrc = W1; FIN = 128; KC = 4;  dstbase = 0;    e = t; }
        else if (t < 24576) { Wsrc = W2; FIN = 512; KC = 16; dstbase = WP2;  e = t - 8192; }
        else                { Wsrc = W3; FIN = 256; KC = 8;  dstbase = WP3;  e = t - 24576; }
        int l    = e & 63, rest = e >> 6;
        int kc   = rest % KC, ot = rest / KC;
        int o    = ot * 16 + (l & 15);
        int k0   = kc * 32 + (l >> 4) * 8;
        const float* s = Wsrc + (size_t)o * FIN + k0;
        float4 a = *(const float4*)s;
        float4 b = *(const float4*)(s + 4);
        __half2 hh[4];
        hh[0] = __floats2half2_rn(a.x, a.y);
        hh[1] = __floats2half2_rn(a.z, a.w);
        hh[2] = __floats2half2_rn(b.x, b.y);
        hh[3] = __floats2half2_rn(b.z, b.w);
        *(float4*)(WpH + dstbase + (size_t)e * 8) = *(float4*)hh;
    }
}

// ---- fused pool + MFMA MLP: 1024 thr = 16 waves, 16 samples, grid N/16.
// R5(this): work-balanced pool. R3 bound wave<->sample, so the straggler
// wave walked ceil(len/64) ~ 4 chunks while the mean is 2.1 and the other
// waves idled at the barrier. Now: block's 16x200 indices + lengths staged
// in LDS, ALL ~33 token-chunks of the block enumerated, waves grab chunks
// round-robin (max 3/wave), per-chunk 128-dim fp32 partials flushed via
// LDS atomicAdd (ds_add_f32, disjoint addrs in-wave). Bytes, 64-token
// batch depth, and the whole MFMA MLP are identical to R3.
__global__ __launch_bounds__(1024, 4) void fused_kernel(
    const int* __restrict__ x, const int* __restrict__ lengths,
    const __half* __restrict__ embH, const __half* __restrict__ WpHh,
    const float* __restrict__ b1, const float* __restrict__ b2,
    const float* __restrict__ b3,
    const float* __restrict__ W4, const float* __restrict__ b4,
    float* __restrict__ out)
{
    __shared__ __align__(16) _Float16 A0[16 * 136];
    __shared__ __align__(16) _Float16 H1[16 * 520];
    __shared__ __align__(16) _Float16 H2[16 * 264];
    __shared__ __align__(16) _Float16 H3[16 * 136];
    __shared__ __align__(16) int      xs[16 * T_TOK];   // block token indices
    __shared__ __align__(16) float    Pf[16][128];      // fp32 pool partials
    __shared__ int lenS[16];

    const _Float16* Wp = (const _Float16*)WpHh;
    const int tid  = threadIdx.x;
    const int wid  = tid >> 6;            // 0..15
    const int lane = tid & 63;
    const int base = blockIdx.x * 16;
    const int n15  = lane & 15;
    const int quad = lane >> 4;
    const int part = lane >> 4;           // 0..3: token stream
    const int sub  = lane & 15;           // 0..15: f16x8 slot in 256B row

    // ---- stage block inputs: lengths, 16x200 indices, zero partials ----
    if (tid < 16) lenS[tid] = lengths[base + tid];
    {
        const int* xg = x + (size_t)base * T_TOK;       // 3200 contiguous ints
        for (int i = tid; i < 16 * T_TOK; i += 1024) xs[i] = xg[i];
        for (int i = tid; i < 16 * 128;  i += 1024) ((float*)Pf)[i] = 0.f;
    }
    __syncthreads();

    // ---- balanced pool: waves grab 64-token chunks round-robin ----
    {
        int TC = 0;                                      // total chunks
#pragma unroll
        for (int s = 0; s < 16; ++s) TC += (lenS[s] + 63) >> 6;

        for (int k = wid; k < TC; k += 16) {
            // map chunk id k -> (sample s, chunk c)
            int kk = k, s = 0;
            int ck = (lenS[0] + 63) >> 6;
            while (kk >= ck) { kk -= ck; ++s; ck = (lenS[s] + 63) >> 6; }
            const int c = kk;
            int m = lenS[s] - c * 64;
            if (m > 64) m = 64;
            const int* xrow = &xs[s * T_TOK + c * 64];

            // one batch: 16 quad-loads in flight = all 64 chunk tokens
            float4 v[16];
#pragma unroll
            for (int i = 0; i < 16; ++i) {
                int t  = 4 * i + part;
                int tc = (t < m) ? t : (m - 1);   // clamp: dup line, L1-hit
                int idx = xrow[tc];               // LDS broadcast read
                v[i] = *(const float4*)(embH + (size_t)idx * EMB + sub * 8);
            }
            float acc[8];
#pragma unroll
            for (int j = 0; j < 8; ++j) acc[j] = 0.f;
#pragma unroll
            for (int i = 0; i < 16; ++i) {
                int t = 4 * i + part;
                if (t < m) {
                    const __half2* h = (const __half2*)&v[i];
#pragma unroll
                    for (int q = 0; q < 4; ++q) {
                        float2 f = __half22float2(h[q]);
                        acc[2 * q]     += f.x;
                        acc[2 * q + 1] += f.y;
                    }
                }
            }
            // reduce the 4 token-streams, flush to sample partials
#pragma unroll
            for (int j = 0; j < 8; ++j) {
                acc[j] += __shfl(acc[j], lane ^ 16);
                acc[j] += __shfl(acc[j], lane ^ 32);
            }
            if (part == 0) {
#pragma unroll
                for (int j = 0; j < 8; ++j)
                    atomicAdd(&Pf[s][sub * 8 + j], acc[j]);
            }
        }
    }
    __syncthreads();

    // ---- finalize pooled vector: wave wid -> sample wid ----
    if (lane < 16) {
        const float inv = 1.0f / (float)lenS[wid];
        const float* p = &Pf[wid][lane * 8];
        float4 a = *(const float4*)p;
        float4 b = *(const float4*)(p + 4);
        __half2 hp[4];
        hp[0] = __floats2half2_rn(a.x * inv, a.y * inv);
        hp[1] = __floats2half2_rn(a.z * inv, a.w * inv);
        hp[2] = __floats2half2_rn(b.x * inv, b.y * inv);
        hp[3] = __floats2half2_rn(b.z * inv, b.w * inv);
        *(float4*)&A0[wid * 136 + lane * 8] = *(float4*)hp;
    }

    // ---- L1 W-frags: issued here; latency hides under the barrier ----
    f16x8 w1f[2][4];
#pragma unroll
    for (int ot = 0; ot < 2; ++ot)
#pragma unroll
        for (int kc = 0; kc < 4; ++kc)
            w1f[ot][kc] = *(const f16x8*)(Wp + ((size_t)(wid * 2 + ot) * 4 + kc) * 512 + lane * 8);

    __syncthreads();

    // ---- L1: 128 -> 512, W in registers ----
    {
        f16x8 a[4];
#pragma unroll
        for (int kc = 0; kc < 4; ++kc)
            a[kc] = *(const f16x8*)&A0[n15 * 136 + kc * 32 + quad * 8];

        f32x4 acc[2];
        acc[0] = (f32x4){0.f, 0.f, 0.f, 0.f};
        acc[1] = (f32x4){0.f, 0.f, 0.f, 0.f};

#pragma unroll
        for (int kc = 0; kc < 4; ++kc)
#pragma unroll
            for (int ot = 0; ot < 2; ++ot)
                acc[ot] = __builtin_amdgcn_mfma_f32_16x16x32_f16(a[kc], w1f[ot][kc], acc[ot], 0, 0, 0);

#pragma unroll
        for (int ot = 0; ot < 2; ++ot) {
            int o = (wid * 2 + ot) * 16 + n15;
            float bias = b1[o];
#pragma unroll
            for (int r = 0; r < 4; ++r) {
                float v = acc[ot][r] + bias;
                H1[(quad * 4 + r) * 520 + o] = (_Float16)fmaxf(v, 0.f);
            }
        }
    }
    __syncthreads();

    // ---- L2: 512 -> 256, kc batched x4 (4 B-frag loads in flight) ----
    {
        f32x4 acc = (f32x4){0.f, 0.f, 0.f, 0.f};
#pragma unroll
        for (int kb = 0; kb < 4; ++kb) {
            f16x8 bfr[4], afr[4];
#pragma unroll
            for (int i = 0; i < 4; ++i) {
                int kc = kb * 4 + i;
                bfr[i] = *(const f16x8*)(Wp + WP2 + ((size_t)wid * 16 + kc) * 512 + lane * 8);
                afr[i] = *(const f16x8*)&H1[n15 * 520 + kc * 32 + quad * 8];
            }
#pragma unroll
            for (int i = 0; i < 4; ++i)
                acc = __builtin_amdgcn_mfma_f32_16x16x32_f16(afr[i], bfr[i], acc, 0, 0, 0);
        }
        int o = wid * 16 + n15;
        float bias = b2[o];
#pragma unroll
        for (int r = 0; r < 4; ++r) {
            float v = acc[r] + bias;
            H2[(quad * 4 + r) * 264 + o] = (_Float16)fmaxf(v, 0.f);
        }
    }
    __syncthreads();

    // ---- L3: 256 -> 128, waves 0..7, all 8 frags batched ----
    if (wid < 8) {
        f16x8 bfr[8], afr[8];
#pragma unroll
        for (int kc = 0; kc < 8; ++kc) {
            bfr[kc] = *(const f16x8*)(Wp + WP3 + ((size_t)wid * 8 + kc) * 512 + lane * 8);
            afr[kc] = *(const f16x8*)&H2[n15 * 264 + kc * 32 + quad * 8];
        }
        f32x4 acc = (f32x4){0.f, 0.f, 0.f, 0.f};
#pragma unroll
        for (int kc = 0; kc < 8; ++kc)
            acc = __builtin_amdgcn_mfma_f32_16x16x32_f16(afr[kc], bfr[kc], acc, 0, 0, 0);

        int o = wid * 16 + n15;
        float bias = b3[o];
#pragma unroll
        for (int r = 0; r < 4; ++r) {
            float v = acc[r] + bias;
            H3[(quad * 4 + r) * 136 + o] = (_Float16)fmaxf(v, 0.f);
        }
    }
    __syncthreads();

    // ---- L4: 128 -> 2 ----
    if (tid < 32) {
        int s = tid >> 1;
        int o = tid & 1;
        float accv = b4[o];
        const _Float16* xr = &H3[s * 136];
        const float* wr = &W4[(size_t)o * EMB];
#pragma unroll 8
        for (int f = 0; f < EMB; ++f) accv = fmaf((float)xr[f], wr[f], accv);
        out[(size_t)(base + s) * 2 + o] = accv;
    }
}

// =============== fallback (no ws): R3-style fused fp32, proven ===============
#define S_TILE 8
template <int FIN, int FOUT, bool RELU>
__device__ __forceinline__ void layerF(const float* __restrict__ sin,
                                       float* __restrict__ sout,
                                       const float* __restrict__ W,
                                       const float* __restrict__ b, int tid)
{
    constexpr int SIN_STR  = FIN + LPAD;
    constexpr int SOUT_STR = FOUT + LPAD;
    constexpr int OPT    = (FOUT > 256) ? (FOUT / 256) : 1;
    constexpr int NO     = FOUT / OPT;
    constexpr int GROUPS = 256 / NO;
    constexpr int SPT    = S_TILE / GROUPS;
    const int o0 = (tid % NO) * OPT;
    const int s0 = (tid / NO) * SPT;
    float acc[OPT][SPT];
#pragma unroll
    for (int i = 0; i < OPT; ++i) {
        float bi = b[o0 + i];
#pragma unroll
        for (int j = 0; j < SPT; ++j) acc[i][j] = bi;
    }
    const float* wr[OPT];
#pragma unroll
    for (int i = 0; i < OPT; ++i) wr[i] = W + (size_t)(o0 + i) * FIN;
    for (int f = 0; f < FIN; f += 4) {
        float4 w[OPT];
#pragma unroll
        for (int i = 0; i < OPT; ++i) w[i] = *(const float4*)(wr[i] + f);
#pragma unroll
        for (int j = 0; j < SPT; ++j) {
            float4 xv = *(const float4*)&sin[(s0 + j) * SIN_STR + f];
#pragma unroll
            for (int i = 0; i < OPT; ++i) {
                acc[i][j] = fmaf(xv.x, w[i].x, acc[i][j]);
                acc[i][j] = fmaf(xv.y, w[i].y, acc[i][j]);
                acc[i][j] = fmaf(xv.z, w[i].z, acc[i][j]);
                acc[i][j] = fmaf(xv.w, w[i].w, acc[i][j]);
            }
        }
    }
#pragma unroll
    for (int j = 0; j < SPT; ++j) {
#pragma unroll
        for (int i = 0; i < OPT; ++i) {
            float v = acc[i][j];
            if (RELU) v = fmaxf(v, 0.f);
            sout[(s0 + j) * SOUT_STR + (o0 + i)] = v;
        }
    }
}

__global__ __launch_bounds__(256) void fused_fallback(
    const int* __restrict__ x, const int* __restrict__ lengths,
    const float* __restrict__ emb,
    const float* __restrict__ W1, const float* __restrict__ b1,
    const float* __restrict__ W2, const float* __restrict__ b2,
    const float* __restrict__ W3, const float* __restrict__ b3,
    const float* __restrict__ W4, const float* __restrict__ b4,
    float* __restrict__ out)
{
    __shared__ float bufA[S_TILE * (256 + LPAD)];
    __shared__ float bufB[S_TILE * (512 + LPAD)];
    const int tid  = threadIdx.x;
    const int wid  = tid >> 6;
    const int lane = tid & 63;
    const int base = blockIdx.x * S_TILE;
    const int half = lane >> 5;
    const int col4 = (lane & 31) * 4;

    for (int sl = 0; sl < 2; ++sl) {
        const int s   = wid * 2 + sl;
        const int n   = base + s;
        const int len = lengths[n];
        const int* xr = x + (size_t)n * T_TOK;
        int r0 = xr[lane];
        int r1 = xr[64 + lane];
        int r2 = xr[128 + lane];
        int r3 = xr[(192 + lane < T_TOK) ? (192 + lane) : (T_TOK - 1)];
        float4 acc = make_float4(0.f, 0.f, 0.f, 0.f);
        for (int c = 0; c < 4; ++c) {
            const int coff = c * 64;
            if (coff >= len) break;
            int m = len - coff;
            if (m > 64) m = 64;
            int r = r0;
            if (c == 1) r = r1;
            if (c == 2) r = r2;
            if (c == 3) r = r3;
            for (int k = 0; k < m; k += 16) {
                float4 v[8];
#pragma unroll
                for (int i = 0; i < 8; ++i) {
                    int t  = k + 2 * i + half;
                    int tc = (t < m) ? t : (m - 1);
                    int idx = __shfl(r, tc);
                    v[i] = *(const float4*)(emb + (size_t)idx * EMB + col4);
                }
#pragma unroll
                for (int i = 0; i < 8; ++i) {
                    if (k + 2 * i + half < m) {
                        acc.x += v[i].x; acc.y += v[i].y;
                        acc.z += v[i].z; acc.w += v[i].w;
                    }
                }
            }
        }
        acc.x += __shfl(acc.x, lane ^ 32);
        acc.y += __shfl(acc.y, lane ^ 32);
        acc.z += __shfl(acc.z, lane ^ 32);
        acc.w += __shfl(acc.w, lane ^ 32);
        if (half == 0) {
            const float inv = 1.0f / (float)len;
            *(float4*)&bufA[s * (EMB + LPAD) + col4] =
                make_float4(acc.x * inv, acc.y * inv, acc.z * inv, acc.w * inv);
        }
    }
    __syncthreads();
    layerF<128, 512, true>(bufA, bufB, W1, b1, tid);
    __syncthreads();
    layerF<512, 256, true>(bufB, bufA, W2, b2, tid);
    __syncthreads();
    layerF<256, 128, true>(bufA, bufB, W3, b3, tid);
    __syncthreads();
    if (tid < 2 * S_TILE) {
        int s = tid >> 1;
        int o = tid & 1;
        float accv = b4[o];
        const float* xr2 = &bufB[s * (EMB + LPAD)];
        const float* wr2 = &W4[(size_t)o * EMB];
#pragma unroll 8
        for (int f = 0; f < EMB; ++f) accv = fmaf(xr2[f], wr2[f], accv);
        out[(size_t)(base + s) * 2 + o] = accv;
    }
}

extern "C" void kernel_launch(void* const* d_in, const int* in_sizes, int n_in,
                              void* d_out, int out_size, void* d_ws, size_t ws_size,
                              hipStream_t stream)
{
    const int*   x       = (const int*)d_in[0];
    const int*   lengths = (const int*)d_in[1];
    const float* emb     = (const float*)d_in[2];
    const float* W1      = (const float*)d_in[3];
    const float* b1      = (const float*)d_in[4];
    const float* W2      = (const float*)d_in[5];
    const float* b2      = (const float*)d_in[6];
    const float* W3      = (const float*)d_in[7];
    const float* b3      = (const float*)d_in[8];
    const float* W4      = (const float*)d_in[9];
    const float* b4      = (const float*)d_in[10];
    float*       out     = (float*)d_out;

    const int N = in_sizes[1];   // 4096

    if (ws_size < WS_NEED) {
        fused_fallback<<<N / S_TILE, 256, 0, stream>>>(x, lengths, emb,
            W1, b1, W2, b2, W3, b3, W4, b4, out);
        return;
    }

    __half* WpH  = (__half*)d_ws;
    __half* embH = (__half*)((char*)d_ws + EMBH_OFF);

    prep_kernel<<<6362, 256, 0, stream>>>(emb, W1, W2, W3, embH, WpH);
    fused_kernel<<<N / 16, 1024, 0, stream>>>(x, lengths, embH, WpH,
                                              b1, b2, b3, W4, b4, out);
}

// Round 6
// 129.594 us; speedup vs baseline: 1.0362x; 1.0362x over previous
//
#include <hip/hip_runtime.h>
#include <hip/hip_fp16.h>

#define T_TOK 200
#define EMB   128
#define LPAD  4

typedef _Float16 f16x8 __attribute__((ext_vector_type(8)));
typedef float    f32x4 __attribute__((ext_vector_type(4)));

// ws layout: Wpack fp16 (458752 B) | embH (25600000 B)
// Wpack fp16 offsets: L1 0, L2 65536, L3 196608 (total 229376 fp16)
#define WP2        65536
#define WP3        196608
#define EMBH_OFF   458752UL
#define WS_NEED    (EMBH_OFF + 25600000UL)

// ---- prep: emb fp32->fp16 + W pack into MFMA B-frag order (R12-proven) ----
__global__ __launch_bounds__(256) void prep_kernel(
    const float* __restrict__ emb,
    const float* __restrict__ W1, const float* __restrict__ W2,
    const float* __restrict__ W3,
    __half* __restrict__ embH, __half* __restrict__ WpH)
{
    int bid = blockIdx.x;
    if (bid < 6250) {
        size_t i = ((size_t)bid * 256 + threadIdx.x) * 8;   // 12.8M floats exact
        float4 a = *(const float4*)(emb + i);
        float4 b = *(const float4*)(emb + i + 4);
        __half2 hh[4];
        hh[0] = __floats2half2_rn(a.x, a.y);
        hh[1] = __floats2half2_rn(a.z, a.w);
        hh[2] = __floats2half2_rn(b.x, b.y);
        hh[3] = __floats2half2_rn(b.z, b.w);
        *(float4*)(embH + i) = *(float4*)hh;
    } else {
        int t = (bid - 6250) * 256 + threadIdx.x;           // < 28672
        const float* Wsrc; int FIN, KC, dstbase, e;
        if (t < 8192)       { Wsrc = W1; FIN = 128; KC = 4;  dstbase = 0;    e = t; }
        else if (t < 24576) { Wsrc = W2; FIN = 512; KC = 16; dstbase = WP2;  e = t - 8192; }
        else                { Wsrc = W3; FIN = 256; KC = 8;  dstbase = WP3;  e = t - 24576; }
        int l    = e & 63, rest = e >> 6;
        int kc   = rest % KC, ot = rest / KC;
        int o    = ot * 16 + (l & 15);
        int k0   = kc * 32 + (l >> 4) * 8;
        const float* s = Wsrc + (size_t)o * FIN + k0;
        float4 a = *(const float4*)s;
        float4 b = *(const float4*)(s + 4);
        __half2 hh[4];
        hh[0] = __floats2half2_rn(a.x, a.y);
        hh[1] = __floats2half2_rn(a.z, a.w);
        hh[2] = __floats2half2_rn(b.x, b.y);
        hh[3] = __floats2half2_rn(b.z, b.w);
        *(float4*)(WpH + dstbase + (size_t)e * 8) = *(float4*)hh;
    }
}

// ---- fused pool + MFMA MLP: 1024 thr = 16 waves, 16 samples, grid N/16.
// R6 = R3 revert (best measured: 129.6 us). Pool structure variants R4/R5
// (2 blocks/CU, balanced chunk queue) were null/negative at constant bytes:
// the pool is at the random-256B-row gather wall (~3.5 TB/s), structure-
// invariant. 64 tokens in flight per wave (16 f16x8 loads/lane); W1 frag
// prefetch after pool hides under the straggler barrier wait.
__global__ __launch_bounds__(1024, 4) void fused_kernel(
    const int* __restrict__ x, const int* __restrict__ lengths,
    const __half* __restrict__ embH, const __half* __restrict__ WpHh,
    const float* __restrict__ b1, const float* __restrict__ b2,
    const float* __restrict__ b3,
    const float* __restrict__ W4, const float* __restrict__ b4,
    float* __restrict__ out)
{
    __shared__ __align__(16) _Float16 A0[16 * 136];
    __shared__ __align__(16) _Float16 H1[16 * 520];
    __shared__ __align__(16) _Float16 H2[16 * 264];
    __shared__ __align__(16) _Float16 H3[16 * 136];

    const _Float16* Wp = (const _Float16*)WpHh;
    const int tid  = threadIdx.x;
    const int wid  = tid >> 6;            // 0..15
    const int lane = tid & 63;
    const int base = blockIdx.x * 16;
    const int n15  = lane & 15;
    const int quad = lane >> 4;

    // ---- pool phase: wave wid pools sample base+wid ----
    {
        const int n   = base + wid;
        const int len = lengths[n];
        const int* xr = x + (size_t)n * T_TOK;

        int r0 = xr[lane];
        int r1 = xr[64 + lane];
        int r2 = xr[128 + lane];
        int r3 = xr[(192 + lane < T_TOK) ? (192 + lane) : (T_TOK - 1)];

        const int part = lane >> 4;       // 0..3: token stream
        const int sub  = lane & 15;       // 0..15: f16x8 slot in 256B row
        float acc[8];
#pragma unroll
        for (int j = 0; j < 8; ++j) acc[j] = 0.f;

        for (int c = 0; c < 4; ++c) {
            const int coff = c * 64;
            if (coff >= len) break;
            int m = len - coff;
            if (m > 64) m = 64;
            int r = r0;
            if (c == 1) r = r1;
            if (c == 2) r = r2;
            if (c == 3) r = r3;

            // one batch: 16 quad-loads in flight = all 64 chunk tokens
            float4 v[16];
#pragma unroll
            for (int i = 0; i < 16; ++i) {
                int t  = 4 * i + part;
                int tc = (t < m) ? t : (m - 1);   // clamp: dup line, L1-hit
                int idx = __shfl(r, tc);
                v[i] = *(const float4*)(embH + (size_t)idx * EMB + sub * 8);
            }
#pragma unroll
            for (int i = 0; i < 16; ++i) {
                int t = 4 * i + part;
                if (t < m) {
                    const __half2* h = (const __half2*)&v[i];
#pragma unroll
                    for (int q = 0; q < 4; ++q) {
                        float2 f = __half22float2(h[q]);
                        acc[2 * q]     += f.x;
                        acc[2 * q + 1] += f.y;
                    }
                }
            }
        }
#pragma unroll
        for (int j = 0; j < 8; ++j) {
            acc[j] += __shfl(acc[j], lane ^ 16);
            acc[j] += __shfl(acc[j], lane ^ 32);
        }
        if (part == 0) {
            const float inv = 1.0f / (float)len;
            __half2 p[4];
            p[0] = __floats2half2_rn(acc[0] * inv, acc[1] * inv);
            p[1] = __floats2half2_rn(acc[2] * inv, acc[3] * inv);
            p[2] = __floats2half2_rn(acc[4] * inv, acc[5] * inv);
            p[3] = __floats2half2_rn(acc[6] * inv, acc[7] * inv);
            *(float4*)&A0[wid * 136 + sub * 8] = *(float4*)p;
        }
    }

    // ---- L1 W-frags: issued after pool; latency hides under the barrier
    //      wait for straggler waves ----
    f16x8 w1f[2][4];
#pragma unroll
    for (int ot = 0; ot < 2; ++ot)
#pragma unroll
        for (int kc = 0; kc < 4; ++kc)
            w1f[ot][kc] = *(const f16x8*)(Wp + ((size_t)(wid * 2 + ot) * 4 + kc) * 512 + lane * 8);

    __syncthreads();

    // ---- L1: 128 -> 512, W in registers ----
    {
        f16x8 a[4];
#pragma unroll
        for (int kc = 0; kc < 4; ++kc)
            a[kc] = *(const f16x8*)&A0[n15 * 136 + kc * 32 + quad * 8];

        f32x4 acc[2];
        acc[0] = (f32x4){0.f, 0.f, 0.f, 0.f};
        acc[1] = (f32x4){0.f, 0.f, 0.f, 0.f};

#pragma unroll
        for (int kc = 0; kc < 4; ++kc)
#pragma unroll
            for (int ot = 0; ot < 2; ++ot)
                acc[ot] = __builtin_amdgcn_mfma_f32_16x16x32_f16(a[kc], w1f[ot][kc], acc[ot], 0, 0, 0);

#pragma unroll
        for (int ot = 0; ot < 2; ++ot) {
            int o = (wid * 2 + ot) * 16 + n15;
            float bias = b1[o];
#pragma unroll
            for (int r = 0; r < 4; ++r) {
                float v = acc[ot][r] + bias;
                H1[(quad * 4 + r) * 520 + o] = (_Float16)fmaxf(v, 0.f);
            }
        }
    }
    __syncthreads();

    // ---- L2: 512 -> 256, kc batched x4 (4 B-frag loads in flight) ----
    {
        f32x4 acc = (f32x4){0.f, 0.f, 0.f, 0.f};
#pragma unroll
        for (int kb = 0; kb < 4; ++kb) {
            f16x8 bfr[4], afr[4];
#pragma unroll
            for (int i = 0; i < 4; ++i) {
                int kc = kb * 4 + i;
                bfr[i] = *(const f16x8*)(Wp + WP2 + ((size_t)wid * 16 + kc) * 512 + lane * 8);
                afr[i] = *(const f16x8*)&H1[n15 * 520 + kc * 32 + quad * 8];
            }
#pragma unroll
            for (int i = 0; i < 4; ++i)
                acc = __builtin_amdgcn_mfma_f32_16x16x32_f16(afr[i], bfr[i], acc, 0, 0, 0);
        }
        int o = wid * 16 + n15;
        float bias = b2[o];
#pragma unroll
        for (int r = 0; r < 4; ++r) {
            float v = acc[r] + bias;
            H2[(quad * 4 + r) * 264 + o] = (_Float16)fmaxf(v, 0.f);
        }
    }
    __syncthreads();

    // ---- L3: 256 -> 128, waves 0..7, all 8 frags batched ----
    if (wid < 8) {
        f16x8 bfr[8], afr[8];
#pragma unroll
        for (int kc = 0; kc < 8; ++kc) {
            bfr[kc] = *(const f16x8*)(Wp + WP3 + ((size_t)wid * 8 + kc) * 512 + lane * 8);
            afr[kc] = *(const f16x8*)&H2[n15 * 264 + kc * 32 + quad * 8];
        }
        f32x4 acc = (f32x4){0.f, 0.f, 0.f, 0.f};
#pragma unroll
        for (int kc = 0; kc < 8; ++kc)
            acc = __builtin_amdgcn_mfma_f32_16x16x32_f16(afr[kc], bfr[kc], acc, 0, 0, 0);

        int o = wid * 16 + n15;
        float bias = b3[o];
#pragma unroll
        for (int r = 0; r < 4; ++r) {
            float v = acc[r] + bias;
            H3[(quad * 4 + r) * 136 + o] = (_Float16)fmaxf(v, 0.f);
        }
    }
    __syncthreads();

    // ---- L4: 128 -> 2 ----
    if (tid < 32) {
        int s = tid >> 1;
        int o = tid & 1;
        float accv = b4[o];
        const _Float16* xr = &H3[s * 136];
        const float* wr = &W4[(size_t)o * EMB];
#pragma unroll 8
        for (int f = 0; f < EMB; ++f) accv = fmaf((float)xr[f], wr[f], accv);
        out[(size_t)(base + s) * 2 + o] = accv;
    }
}

// =============== fallback (no ws): R3-style fused fp32, proven ===============
#define S_TILE 8
template <int FIN, int FOUT, bool RELU>
__device__ __forceinline__ void layerF(const float* __restrict__ sin,
                                       float* __restrict__ sout,
                                       const float* __restrict__ W,
                                       const float* __restrict__ b, int tid)
{
    constexpr int SIN_STR  = FIN + LPAD;
    constexpr int SOUT_STR = FOUT + LPAD;
    constexpr int OPT    = (FOUT > 256) ? (FOUT / 256) : 1;
    constexpr int NO     = FOUT / OPT;
    constexpr int GROUPS = 256 / NO;
    constexpr int SPT    = S_TILE / GROUPS;
    const int o0 = (tid % NO) * OPT;
    const int s0 = (tid / NO) * SPT;
    float acc[OPT][SPT];
#pragma unroll
    for (int i = 0; i < OPT; ++i) {
        float bi = b[o0 + i];
#pragma unroll
        for (int j = 0; j < SPT; ++j) acc[i][j] = bi;
    }
    const float* wr[OPT];
#pragma unroll
    for (int i = 0; i < OPT; ++i) wr[i] = W + (size_t)(o0 + i) * FIN;
    for (int f = 0; f < FIN; f += 4) {
        float4 w[OPT];
#pragma unroll
        for (int i = 0; i < OPT; ++i) w[i] = *(const float4*)(wr[i] + f);
#pragma unroll
        for (int j = 0; j < SPT; ++j) {
            float4 xv = *(const float4*)&sin[(s0 + j) * SIN_STR + f];
#pragma unroll
            for (int i = 0; i < OPT; ++i) {
                acc[i][j] = fmaf(xv.x, w[i].x, acc[i][j]);
                acc[i][j] = fmaf(xv.y, w[i].y, acc[i][j]);
                acc[i][j] = fmaf(xv.z, w[i].z, acc[i][j]);
                acc[i][j] = fmaf(xv.w, w[i].w, acc[i][j]);
            }
        }
    }
#pragma unroll
    for (int j = 0; j < SPT; ++j) {
#pragma unroll
        for (int i = 0; i < OPT; ++i) {
            float v = acc[i][j];
            if (RELU) v = fmaxf(v, 0.f);
            sout[(s0 + j) * SOUT_STR + (o0 + i)] = v;
        }
    }
}

__global__ __launch_bounds__(256) void fused_fallback(
    const int* __restrict__ x, const int* __restrict__ lengths,
    const float* __restrict__ emb,
    const float* __restrict__ W1, const float* __restrict__ b1,
    const float* __restrict__ W2, const float* __restrict__ b2,
    const float* __restrict__ W3, const float* __restrict__ b3,
    const float* __restrict__ W4, const float* __restrict__ b4,
    float* __restrict__ out)
{
    __shared__ float bufA[S_TILE * (256 + LPAD)];
    __shared__ float bufB[S_TILE * (512 + LPAD)];
    const int tid  = threadIdx.x;
    const int wid  = tid >> 6;
    const int lane = tid & 63;
    const int base = blockIdx.x * S_TILE;
    const int half = lane >> 5;
    const int col4 = (lane & 31) * 4;

    for (int sl = 0; sl < 2; ++sl) {
        const int s   = wid * 2 + sl;
        const int n   = base + s;
        const int len = lengths[n];
        const int* xr = x + (size_t)n * T_TOK;
        int r0 = xr[lane];
        int r1 = xr[64 + lane];
        int r2 = xr[128 + lane];
        int r3 = xr[(192 + lane < T_TOK) ? (192 + lane) : (T_TOK - 1)];
        float4 acc = make_float4(0.f, 0.f, 0.f, 0.f);
        for (int c = 0; c < 4; ++c) {
            const int coff = c * 64;
            if (coff >= len) break;
            int m = len - coff;
            if (m > 64) m = 64;
            int r = r0;
            if (c == 1) r = r1;
            if (c == 2) r = r2;
            if (c == 3) r = r3;
            for (int k = 0; k < m; k += 16) {
                float4 v[8];
#pragma unroll
                for (int i = 0; i < 8; ++i) {
                    int t  = k + 2 * i + half;
                    int tc = (t < m) ? t : (m - 1);
                    int idx = __shfl(r, tc);
                    v[i] = *(const float4*)(emb + (size_t)idx * EMB + col4);
                }
#pragma unroll
                for (int i = 0; i < 8; ++i) {
                    if (k + 2 * i + half < m) {
                        acc.x += v[i].x; acc.y += v[i].y;
                        acc.z += v[i].z; acc.w += v[i].w;
                    }
                }
            }
        }
        acc.x += __shfl(acc.x, lane ^ 32);
        acc.y += __shfl(acc.y, lane ^ 32);
        acc.z += __shfl(acc.z, lane ^ 32);
        acc.w += __shfl(acc.w, lane ^ 32);
        if (half == 0) {
            const float inv = 1.0f / (float)len;
            *(float4*)&bufA[s * (EMB + LPAD) + col4] =
                make_float4(acc.x * inv, acc.y * inv, acc.z * inv, acc.w * inv);
        }
    }
    __syncthreads();
    layerF<128, 512, true>(bufA, bufB, W1, b1, tid);
    __syncthreads();
    layerF<512, 256, true>(bufB, bufA, W2, b2, tid);
    __syncthreads();
    layerF<256, 128, true>(bufA, bufB, W3, b3, tid);
    __syncthreads();
    if (tid < 2 * S_TILE) {
        int s = tid >> 1;
        int o = tid & 1;
        float accv = b4[o];
        const float* xr2 = &bufB[s * (EMB + LPAD)];
        const float* wr2 = &W4[(size_t)o * EMB];
#pragma unroll 8
        for (int f = 0; f < EMB; ++f) accv = fmaf(xr2[f], wr2[f], accv);
        out[(size_t)(base + s) * 2 + o] = accv;
    }
}

extern "C" void kernel_launch(void* const* d_in, const int* in_sizes, int n_in,
                              void* d_out, int out_size, void* d_ws, size_t ws_size,
                              hipStream_t stream)
{
    const int*   x       = (const int*)d_in[0];
    const int*   lengths = (const int*)d_in[1];
    const float* emb     = (const float*)d_in[2];
    const float* W1      = (const float*)d_in[3];
    const float* b1      = (const float*)d_in[4];
    const float* W2      = (const float*)d_in[5];
    const float* b2      = (const float*)d_in[6];
    const float* W3      = (const float*)d_in[7];
    const float* b3      = (const float*)d_in[8];
    const float* W4      = (const float*)d_in[9];
    const float* b4      = (const float*)d_in[10];
    float*       out     = (float*)d_out;

    const int N = in_sizes[1];   // 4096

    if (ws_size < WS_NEED) {
        fused_fallback<<<N / S_TILE, 256, 0, stream>>>(x, lengths, emb,
            W1, b1, W2, b2, W3, b3, W4, b4, out);
        return;
    }

    __half* WpH  = (__half*)d_ws;
    __half* embH = (__half*)((char*)d_ws + EMBH_OFF);

    prep_kernel<<<6362, 256, 0, stream>>>(emb, W1, W2, W3, embH, WpH);
    fused_kernel<<<N / 16, 1024, 0, stream>>>(x, lengths, embH, WpH,
                                              b1, b2, b3, W4, b4, out);
}